// Round 3
// baseline (37.163 us; speedup 1.0000x reference)
//
#include <hip/hip_runtime.h>
#include <hip/hip_bf16.h>

// RGCN layer (R=8, B=4, N=1024, I=O=64, NB=4) on MI355X.
//
// Slot folding (round 1): out[o] = relu(bias[o] + sum_{j=9o..9o+8} concat[j]).
// Channel c of relation r contributes to o=(64r+c)/9 -> slot s=(r+c)/9 in [0,8).
// aggX[b][n][72]: relation r slot s at 8r+s = o+r, self at 64+s = o+8.
//
//  prep_kernel : 256 blocks; w~ fold; x~T[rb][16][1024] bf16 via MFMA
//                (vector stores via LDS bounce); r==0 blocks also do the
//                self-loop pass -> aggX[b][n][64+s]; zeroes deg.
//  agg_kernel  : 512 blocks x 256 thr (2/CU). 64-row K-steps (16 barriers),
//                2-step-deep named-reg prefetch, b64 packed transpose writes
//                with ((n&7)^(n>>3)) XOR swizzle, 4-wave deg reduce + atomic.
//  out_kernel  : out[o] = relu(bias + aggX[o+r1]/deg + [r2!=r1] aggX[o+r2]/deg).

#define NN 1024
#define EPSK 1e-7f

typedef __bf16 bf16x8 __attribute__((ext_vector_type(8)));
typedef float f32x4 __attribute__((ext_vector_type(4)));

__device__ __forceinline__ unsigned short f2bf(float f) {
  union { float f; unsigned int u; } v; v.f = f;
  return (unsigned short)((v.u + 0x7FFFu + ((v.u >> 16) & 1u)) >> 16);
}

// ---------------------------------------------------------------------------
// prep: 256 blocks x 256 thr. (r,b,chunk); r==0 blocks also run self pass.
// ---------------------------------------------------------------------------
__global__ __launch_bounds__(256) void prep_kernel(
    const float* __restrict__ feat,    // [4,1024,64]
    const float* __restrict__ weight,  // [4,64,64]
    const float* __restrict__ Wo,      // [64,64]
    const float* __restrict__ wcmp,    // [8,4]
    unsigned short* __restrict__ xT,   // [32][16][1024] bf16 (slots 8..15 = 0)
    float* __restrict__ aggX,          // [4][1024][72] f32
    float* __restrict__ deg)           // [32][1024] f32
{
  __shared__ __align__(16) unsigned short featL[128 * 72];  // [n][i] bf16
  __shared__ __align__(16) float wTf[64 * 65];              // [c][i] f32
  __shared__ __align__(16) unsigned short wfold[16 * 72];   // [s][i] bf16
  __shared__ __align__(16) unsigned short stg[16 * 136];    // [s][n] bounce

  const int bid = blockIdx.x;
  const int t = threadIdx.x;
  const int r = bid >> 5, b = (bid >> 3) & 3, chunk = bid & 7;
  const int n0 = chunk << 7;

  if (bid < 32) {
    for (int k = t; k < NN; k += 256) deg[bid * NN + k] = 0.0f;
  }

  // stage features chunk [128 n][64 i] -> bf16 LDS
  const float* fsrc = feat + ((size_t)(b * NN + n0)) * 64;
  #pragma unroll
  for (int p = 0; p < 8; ++p) {
    const int idx = p * 256 + t;
    const int row = idx >> 4, c4 = idx & 15;
    const float4 v = *reinterpret_cast<const float4*>(fsrc + row * 64 + c4 * 4);
    ushort4 u;
    u.x = f2bf(v.x); u.y = f2bf(v.y); u.z = f2bf(v.z); u.w = f2bf(v.w);
    *reinterpret_cast<ushort4*>(&featL[row * 72 + c4 * 4]) = u;
  }

  // wTf[c][i] = w_full[i][c] for relation r
  {
    const float wc0 = wcmp[r * 4 + 0], wc1 = wcmp[r * 4 + 1];
    const float wc2 = wcmp[r * 4 + 2], wc3 = wcmp[r * 4 + 3];
    #pragma unroll
    for (int jj = 0; jj < 16; ++jj) {
      const int e = jj * 256 + t;
      const int i = e >> 6, c = e & 63;
      wTf[c * 65 + i] = wc0 * weight[i * 64 + c] + wc1 * weight[4096 + i * 64 + c] +
                        wc2 * weight[8192 + i * 64 + c] + wc3 * weight[12288 + i * 64 + c];
    }
  }
  __syncthreads();

  // fold: wfold[s][i] = sum_{c : (r+c)/9 == s} wTf[c][i]
  #pragma unroll
  for (int jj = 0; jj < 4; ++jj) {
    const int e = jj * 256 + t;
    const int s = e >> 6, i = e & 63;
    float sum = 0.f;
    if (s < 8) {
      const int c0 = 9 * s - r;
      const int clo = c0 < 0 ? 0 : c0;
      const int chi = (c0 + 8 > 63) ? 63 : c0 + 8;
      for (int c = clo; c <= chi; ++c) sum += wTf[c * 65 + i];
    }
    wfold[s * 72 + i] = f2bf(sum);
  }
  __syncthreads();

  const int w = t >> 6, lane = t & 63;
  const int li = lane & 15, lg = lane >> 4;

  // MFMA: D[slot][n] = sum_i wfold[slot][i] * featL[n][i]
  f32x4 acc0 = {0.f, 0.f, 0.f, 0.f}, acc1 = {0.f, 0.f, 0.f, 0.f};
  #pragma unroll
  for (int ks = 0; ks < 2; ++ks) {
    const int kof = ks * 32 + lg * 8;
    const bf16x8 af = __builtin_bit_cast(bf16x8,
        *reinterpret_cast<const uint4*>(&wfold[li * 72 + kof]));
    const bf16x8 b0 = __builtin_bit_cast(bf16x8,
        *reinterpret_cast<const uint4*>(&featL[((2 * w + 0) * 16 + li) * 72 + kof]));
    const bf16x8 b1 = __builtin_bit_cast(bf16x8,
        *reinterpret_cast<const uint4*>(&featL[((2 * w + 1) * 16 + li) * 72 + kof]));
    acc0 = __builtin_amdgcn_mfma_f32_16x16x32_bf16(af, b0, acc0, 0, 0, 0);
    acc1 = __builtin_amdgcn_mfma_f32_16x16x32_bf16(af, b1, acc1, 0, 0, 0);
  }
  // bounce D[slot = lg*4+qq][n = tile*16+li] into stg, then vector store
  #pragma unroll
  for (int qq = 0; qq < 4; ++qq) {
    const int s = lg * 4 + qq;
    stg[s * 136 + (2 * w + 0) * 16 + li] = f2bf(acc0[qq]);
    stg[s * 136 + (2 * w + 1) * 16 + li] = f2bf(acc1[qq]);
  }
  __syncthreads();
  {
    const int slot = t >> 4, seg = t & 15;
    *reinterpret_cast<uint4*>(xT + ((size_t)(r * 4 + b) << 14) + slot * NN + n0 + seg * 8) =
        *reinterpret_cast<const uint4*>(&stg[slot * 136 + seg * 8]);
  }

  // self-loop pass on r==0 blocks (featL still valid)
  if (r == 0) {
    #pragma unroll
    for (int jj = 0; jj < 16; ++jj) {
      const int e = jj * 256 + t;
      const int i = e >> 6, c = e & 63;
      wTf[c * 65 + i] = Wo[i * 64 + c];
    }
    __syncthreads();
    #pragma unroll
    for (int jj = 0; jj < 4; ++jj) {
      const int e = jj * 256 + t;
      const int s = e >> 6, i = e & 63;
      float sum = 0.f;
      if (s < 8) {
        const int c0 = 9 * s - 8;
        const int clo = c0 < 0 ? 0 : c0;
        const int chi = (c0 + 8 > 63) ? 63 : c0 + 8;
        for (int c = clo; c <= chi; ++c) sum += wTf[c * 65 + i];
      }
      wfold[s * 72 + i] = f2bf(sum);
    }
    __syncthreads();
    f32x4 sa0 = {0.f, 0.f, 0.f, 0.f}, sa1 = {0.f, 0.f, 0.f, 0.f};
    #pragma unroll
    for (int ks = 0; ks < 2; ++ks) {
      const int kof = ks * 32 + lg * 8;
      const bf16x8 af = __builtin_bit_cast(bf16x8,
          *reinterpret_cast<const uint4*>(&wfold[li * 72 + kof]));
      const bf16x8 b0 = __builtin_bit_cast(bf16x8,
          *reinterpret_cast<const uint4*>(&featL[((2 * w + 0) * 16 + li) * 72 + kof]));
      const bf16x8 b1 = __builtin_bit_cast(bf16x8,
          *reinterpret_cast<const uint4*>(&featL[((2 * w + 1) * 16 + li) * 72 + kof]));
      sa0 = __builtin_amdgcn_mfma_f32_16x16x32_bf16(af, b0, sa0, 0, 0, 0);
      sa1 = __builtin_amdgcn_mfma_f32_16x16x32_bf16(af, b1, sa1, 0, 0, 0);
    }
    #pragma unroll
    for (int qq = 0; qq < 4; ++qq) {
      const int s = lg * 4 + qq;
      if (s < 8) {
        aggX[((size_t)(b * NN + n0 + (2 * w + 0) * 16 + li)) * 72 + 64 + s] = sa0[qq];
        aggX[((size_t)(b * NN + n0 + (2 * w + 1) * 16 + li)) * 72 + 64 + s] = sa1[qq];
      }
    }
  }
}

// ---------------------------------------------------------------------------
// agg: 512 blocks x 256 thr (2 blocks/CU). 64-row steps, 16 barriers.
// ---------------------------------------------------------------------------
#define AGG_STEP(P0, P1, P2, P3, S)                                               \
  {                                                                               \
    const int s_ = (S);                                                           \
    const int buf_ = s_ & 1;                                                      \
    unsigned char* at_ = &adjTB[buf_][0];                                         \
    const int r0_[4] = {P0.x, P0.y, P0.z, P0.w};                                  \
    const int r1_[4] = {P1.x, P1.y, P1.z, P1.w};                                  \
    const int r2_[4] = {P2.x, P2.y, P2.z, P2.w};                                  \
    const int r3_[4] = {P3.x, P3.y, P3.z, P3.w};                                  \
    _Pragma("unroll")                                                             \
    for (int jj = 0; jj < 4; ++jj) {                                              \
      const int n_ = 4 * q + jj;                                                  \
      const int key_ = ((n_ & 7) ^ ((n_ >> 3) & 7)) & 7;                          \
      uint2 v_;                                                                   \
      v_.x = (r0_[jj] ? 0x3F80u : 0u) | (r1_[jj] ? 0x3F800000u : 0u);             \
      v_.y = (r2_[jj] ? 0x3F80u : 0u) | (r3_[jj] ? 0x3F800000u : 0u);             \
      *reinterpret_cast<uint2*>(at_ + n_ * 128 + ((mp * 8) ^ (key_ << 4))) = v_;  \
    }                                                                             \
    degP[buf_][4 * mp + 0][q] = (float)(r0_[0] + r0_[1] + r0_[2] + r0_[3]);       \
    degP[buf_][4 * mp + 1][q] = (float)(r1_[0] + r1_[1] + r1_[2] + r1_[3]);       \
    degP[buf_][4 * mp + 2][q] = (float)(r2_[0] + r2_[1] + r2_[2] + r2_[3]);       \
    degP[buf_][4 * mp + 3][q] = (float)(r3_[0] + r3_[1] + r3_[2] + r3_[3]);       \
    if (s_ < 14) {                                                                \
      const int* ns_ = asrc + ((size_t)((s_ + 2) * 64 + 4 * mp) << 10);           \
      P0 = *reinterpret_cast<const int4*>(ns_);                                   \
      P1 = *reinterpret_cast<const int4*>(ns_ + 1024);                            \
      P2 = *reinterpret_cast<const int4*>(ns_ + 2048);                            \
      P3 = *reinterpret_cast<const int4*>(ns_ + 3072);                            \
    }                                                                             \
    asm volatile("s_waitcnt lgkmcnt(0)" ::: "memory");                            \
    __builtin_amdgcn_s_barrier();                                                 \
    {                                                                             \
      const int row_ = w * 16 + (lane >> 2), k4_ = lane & 3;                      \
      const float4 f_ =                                                           \
          *reinterpret_cast<const float4*>(&degP[buf_][row_][k4_ * 4]);           \
      float sum_ = f_.x + f_.y + f_.z + f_.w;                                     \
      sum_ += __shfl_xor(sum_, 1, 64);                                            \
      sum_ += __shfl_xor(sum_, 2, 64);                                            \
      if (k4_ == 0) atomicAdd(&deg[rb * NN + s_ * 64 + row_], sum_);              \
    }                                                                             \
    _Pragma("unroll")                                                             \
    for (int h_ = 0; h_ < 2; ++h_) {                                              \
      const bf16x8 af_ = __builtin_bit_cast(bf16x8,                               \
          *reinterpret_cast<const uint4*>(                                        \
              at_ + arow * 128 + ((h_ * 64 + lg * 16) ^ (keyA << 4))));           \
      uint4 br_ = make_uint4(0u, 0u, 0u, 0u);                                     \
      if (li < 8)                                                                 \
        br_ = *reinterpret_cast<const uint4*>(&xlds[xbase + h_ * 32 + s_ * 64]);  \
      acc = __builtin_amdgcn_mfma_f32_16x16x32_bf16(                              \
          af_, __builtin_bit_cast(bf16x8, br_), acc, 0, 0, 0);                    \
    }                                                                             \
  }

__global__ __launch_bounds__(256) void agg_kernel(
    const int* __restrict__ adj,            // [32][1024][1024]
    const unsigned short* __restrict__ xT,  // [32][16][1024] bf16
    float* __restrict__ aggX,               // [4][1024][72]
    float* __restrict__ deg)                // [32][1024]
{
  __shared__ __align__(16) unsigned short xlds[16 * 1040];  // [slot][m]
  __shared__ __align__(16) unsigned char adjTB[2][64 * 128]; // [n][m^swz] bf16
  __shared__ __align__(16) float degP[2][64][20];

  const int bid = blockIdx.x;
  const int rb = bid >> 4, r = rb >> 2, b = rb & 3;
  const int ncol0 = (bid & 15) << 6;
  const int t = threadIdx.x;
  const int q = t & 15, mp = t >> 4;  // col-quad, m-quad

  const int* asrc = adj + (((size_t)rb) << 20) + ncol0 + (q << 2);

  // prefetch steps 0 and 1 (issued before staging loads -> oldest in queue)
  int4 pa0 = *reinterpret_cast<const int4*>(asrc + ((size_t)(4 * mp + 0) << 10));
  int4 pa1 = *reinterpret_cast<const int4*>(asrc + ((size_t)(4 * mp + 1) << 10));
  int4 pa2 = *reinterpret_cast<const int4*>(asrc + ((size_t)(4 * mp + 2) << 10));
  int4 pa3 = *reinterpret_cast<const int4*>(asrc + ((size_t)(4 * mp + 3) << 10));
  int4 pb0 = *reinterpret_cast<const int4*>(asrc + ((size_t)(64 + 4 * mp + 0) << 10));
  int4 pb1 = *reinterpret_cast<const int4*>(asrc + ((size_t)(64 + 4 * mp + 1) << 10));
  int4 pb2 = *reinterpret_cast<const int4*>(asrc + ((size_t)(64 + 4 * mp + 2) << 10));
  int4 pb3 = *reinterpret_cast<const int4*>(asrc + ((size_t)(64 + 4 * mp + 3) << 10));

  // stage x~ panel (32 KB) into LDS, stride 1040
  const unsigned short* xs = xT + (((size_t)rb) << 14);
  #pragma unroll
  for (int it = 0; it < 8; ++it) {
    const int idx = t + (it << 8);
    const int row = idx >> 7, seg = idx & 127;
    *reinterpret_cast<uint4*>(&xlds[row * 1040 + seg * 8]) =
        *reinterpret_cast<const uint4*>(xs + row * NN + seg * 8);
  }

  const int w = t >> 6, lane = t & 63;
  const int li = lane & 15, lg = lane >> 4;
  const int arow = w * 16 + li;
  const int keyA = ((arow & 7) ^ ((arow >> 3) & 7)) & 7;
  const int xbase = li * 1040 + lg * 8;

  f32x4 acc = {0.f, 0.f, 0.f, 0.f};

  for (int tt = 0; tt < 8; ++tt) {
    AGG_STEP(pa0, pa1, pa2, pa3, 2 * tt);
    AGG_STEP(pb0, pb1, pb2, pb3, 2 * tt + 1);
  }

  // lane holds D[n = w*16 + lg*4 + qq][slot = li] (slots 0..7 valid)
  float* dst = aggX + ((size_t)(b * NN + ncol0)) * 72 + r * 8;
  if (li < 8) {
    #pragma unroll
    for (int qq = 0; qq < 4; ++qq) {
      const int n = w * 16 + lg * 4 + qq;
      dst[(size_t)n * 72 + li] = acc[qq];
    }
  }
}

// ---------------------------------------------------------------------------
// epilogue
// ---------------------------------------------------------------------------
__global__ __launch_bounds__(256) void out_kernel(
    const float* __restrict__ aggX, const float* __restrict__ deg,
    const float* __restrict__ bias, float* __restrict__ out)
{
  const int gid = blockIdx.x * 256 + threadIdx.x;
  const int o = gid & 63;
  const int n = (gid >> 6) & 1023;
  const int b = gid >> 16;
  const float* cp = aggX + ((size_t)(b * NN + n)) * 72;

  const int r1 = (9 * o) >> 6;
  const int r2 = (9 * o + 8) >> 6;

  float v1 = cp[o + r1];
  if (r1 < 8) v1 /= (deg[(r1 * 4 + b) * NN + n] + EPSK);
  float acc = bias[o] + v1;
  if (r2 != r1) {
    float v2 = cp[o + r2];
    if (r2 < 8) v2 /= (deg[(r2 * 4 + b) * NN + n] + EPSK);
    acc += v2;
  }
  out[gid] = fmaxf(acc, 0.0f);
}

extern "C" void kernel_launch(void* const* d_in, const int* in_sizes, int n_in,
                              void* d_out, int out_size, void* d_ws, size_t ws_size,
                              hipStream_t stream) {
  const float* feat   = (const float*)d_in[0];
  const int*   adj    = (const int*)d_in[1];
  const float* weight = (const float*)d_in[2];
  const float* Wo     = (const float*)d_in[3];
  const float* wcmp   = (const float*)d_in[4];
  const float* bias   = (const float*)d_in[5];
  float* out = (float*)d_out;

  // ws layout: x~T (1 MiB bf16) | aggX (1.125 MiB f32) | deg (128 KiB f32)
  char* ws = (char*)d_ws;
  unsigned short* xT = (unsigned short*)(ws);
  float* aggX = (float*)(ws + 1048576u);
  float* deg  = (float*)(ws + 1048576u + 1179648u);

  prep_kernel<<<dim3(256), dim3(256), 0, stream>>>(feat, weight, Wo, wcmp, xT, aggX, deg);
  agg_kernel<<<dim3(512), dim3(256), 0, stream>>>(adj, xT, aggX, deg);
  out_kernel<<<dim3(1024), dim3(256), 0, stream>>>(aggX, deg, bias, out);
}